// Round 12
// baseline (265.943 us; speedup 1.0000x reference)
//
#include <hip/hip_runtime.h>

#define NN 50000
#define NE 800000
#define IN_C 256
#define HID_C 256
#define OUT_C 128

#define NETP (NE + 8 * NN)  // padded csr capacity: sum round_up(deg+1,8) <= NE+8*NN
#define NBUCK 196   // ceil(NN/256) buckets of 256 nodes (by col)
#define CHUNK 4096  // edges per pass-A block
#define NPA 196     // ceil(NE/CHUNK)
#define CAP_B 6400  // pass-B LDS capacity in slots (padded bucket mean ~5350, sigma ~56)

typedef unsigned short u16;
typedef unsigned int u32;
typedef __attribute__((ext_vector_type(8))) short short8;
typedef __attribute__((ext_vector_type(8))) unsigned short ushort8;
typedef __attribute__((ext_vector_type(4))) float f32x4;
typedef __attribute__((ext_vector_type(2))) float f32x2;
typedef __attribute__((ext_vector_type(4))) unsigned u32x4;

// planar plane stride (u16 units): 32 ch x (NN+1) rows, zero row at index NN
#define CPS ((size_t)(NN + 1) * 32)

__device__ __forceinline__ u16 f2b(float f) {
  unsigned int u = __float_as_uint(f);
  return (u16)((u + 0x7FFFu + ((u >> 16) & 1u)) >> 16);  // RNE
}
__device__ __forceinline__ float b2f(u16 s) {
  return __uint_as_float(((unsigned int)s) << 16);
}

// ---------------- fused: weight convert+transpose, cnt init(=1 self), Hb zero rows ----------------

__global__ __launch_bounds__(256) void convw_zero(const float* __restrict__ W1,
                                                  const float* __restrict__ W2,
                                                  u16* __restrict__ W1t,
                                                  u16* __restrict__ W2t,
                                                  int* __restrict__ cnt,
                                                  u16* __restrict__ Hb,
                                                  int nzb) {
  int b = blockIdx.x;
  if (b < 256) {
    int id = b * 256 + threadIdx.x;
    if (id < 256 * 256) {
      int n = id >> 8, k = id & 255;
      W1t[id] = f2b(W1[k * 256 + n]);
    }
    if (id < 128 * 256) {
      int n = id >> 8, k = id & 255;
      W2t[id] = f2b(W2[k * 128 + n]);
    }
  } else if (b < 256 + nzb) {
    int i = (b - 256) * 256 + threadIdx.x;
    if (i < NN) cnt[i] = 1;  // self-loop included in CSR
  } else {
    // zero row at tail of each of the 8 Hb planes (absorbs pad-slot gathers)
    int t = threadIdx.x;  // 256 threads = 8 planes x 32 ch
    Hb[(size_t)(t >> 5) * CPS + (size_t)NN * 32 + (t & 31)] = 0;
  }
}

// ---------------- CSR build ----------------

__global__ __launch_bounds__(256) void hist_kernel(const int* __restrict__ col,
                                                   int* __restrict__ cnt, int E) {
  int e = blockIdx.x * blockDim.x + threadIdx.x;
  if (e < E) atomicAdd(&cnt[col[e]], 1);
}

// scan over PADDED per-node sizes: pad(v) = round_up(v,8)
__global__ __launch_bounds__(256) void scan1_kernel(const int* __restrict__ cnt,
                                                    int* __restrict__ bsum, int n) {
  __shared__ int ws[4];
  int i = blockIdx.x * 256 + threadIdx.x;
  int lane = threadIdx.x & 63, wid = threadIdx.x >> 6;
  int v = (i < n) ? ((cnt[i] + 7) & ~7) : 0;
#pragma unroll
  for (int off = 32; off > 0; off >>= 1) v += __shfl_down(v, off, 64);
  if (lane == 0) ws[wid] = v;
  __syncthreads();
  if (threadIdx.x == 0) bsum[blockIdx.x] = ws[0] + ws[1] + ws[2] + ws[3];
}

__global__ __launch_bounds__(256) void scan2_kernel(const int* __restrict__ bsum,
                                                    int* __restrict__ boff,
                                                    int* __restrict__ row_off,
                                                    int nb, int n) {
  __shared__ int wsum[4], wpre[5];
  int lane = threadIdx.x & 63, wid = threadIdx.x >> 6;
  int v = (threadIdx.x < nb) ? bsum[threadIdx.x] : 0;
  int s = v;
#pragma unroll
  for (int off = 1; off < 64; off <<= 1) {
    int t = __shfl_up(s, off, 64);
    if (lane >= off) s += t;
  }
  if (lane == 63) wsum[wid] = s;
  __syncthreads();
  if (threadIdx.x == 0) {
    int acc = 0;
#pragma unroll
    for (int w = 0; w < 4; ++w) { wpre[w] = acc; acc += wsum[w]; }
    wpre[4] = acc;
  }
  __syncthreads();
  if (threadIdx.x < nb) boff[threadIdx.x] = wpre[wid] + (s - v);
  if (threadIdx.x == 0) row_off[n] = wpre[4];
}

// scan3: padded offsets into row_off; bcur[b] = row_off[b*256]; dinv from RAW count
__global__ __launch_bounds__(256) void scan3_kernel(const int* __restrict__ cnt,
                                                    const int* __restrict__ boff,
                                                    int* __restrict__ row_off,
                                                    int* __restrict__ bcur,
                                                    float* __restrict__ dinv, int n) {
  __shared__ int wsum[4], wpre[4];
  int i = blockIdx.x * 256 + threadIdx.x;
  int lane = threadIdx.x & 63, wid = threadIdx.x >> 6;
  int vr = (i < n) ? cnt[i] : 0;       // raw deg+1
  int v = (vr + 7) & ~7;               // padded
  int s = v;
#pragma unroll
  for (int off = 1; off < 64; off <<= 1) {
    int t = __shfl_up(s, off, 64);
    if (lane >= off) s += t;
  }
  if (lane == 63) wsum[wid] = s;
  __syncthreads();
  if (threadIdx.x == 0) {
    int acc = 0;
#pragma unroll
    for (int w = 0; w < 4; ++w) { wpre[w] = acc; acc += wsum[w]; }
  }
  __syncthreads();
  if (i < n) {
    int off = boff[blockIdx.x] + wpre[wid] + (s - v);
    row_off[i] = off;
    if ((i & 255) == 0) bcur[i >> 8] = off;
    dinv[i] = rsqrtf((float)vr);
  }
}

// ---------------- MFMA GEMM body (shared by plain and fused kernels) ----------------
// PLANAR_C: C write remapped to [gc>>5][gr][gc&31] planes of stride CPS.

template <bool A_IS_F32, bool PLANAR_C>
__device__ __forceinline__ void gemm_body(const void* __restrict__ Ap,
                                          const u16* __restrict__ Bt,
                                          const float* __restrict__ dscale,
                                          u16* __restrict__ C, int M, int N,
                                          int bx, int by,
                                          u16 (&Asl)[2][5120], u16 (&Bsl)[2][5120]) {
  const int tid = threadIdx.x;
  const int row0 = by * 128;
  const int col0 = bx * 128;

  f32x4 acc[4][4] = {};

  const int seg = tid & 7;
  const int rb = tid >> 3;
  const int wave = tid >> 6, lane = tid & 63;
  const int wm = wave >> 1, wn = wave & 1;
  const int qr = lane & 15, quad = lane >> 4;

  float4 aF[4];
  ushort4 aU[4];
  ushort4 bR[4];

  auto load_tiles = [&](int k0) {
    if constexpr (A_IS_F32) {
      const float* A = (const float*)Ap;
#pragma unroll
      for (int i = 0; i < 4; ++i) {
        int gr = row0 + rb + i * 32;
        aF[i] = (gr < M) ? *(const float4*)&A[(size_t)gr * 256 + k0 + seg * 4]
                         : make_float4(0.f, 0.f, 0.f, 0.f);
      }
    } else {
      const u16* A = (const u16*)Ap;
#pragma unroll
      for (int i = 0; i < 4; ++i) {
        int gr = row0 + rb + i * 32;
        aU[i] = (gr < M) ? *(const ushort4*)&A[(size_t)gr * 256 + k0 + seg * 4]
                         : make_ushort4(0, 0, 0, 0);
      }
    }
#pragma unroll
    for (int i = 0; i < 4; ++i) {
      int n = rb + i * 32;
      bR[i] = *(const ushort4*)&Bt[(size_t)(col0 + n) * 256 + k0 + seg * 4];
    }
  };

  auto write_lds = [&](int buf) {
#pragma unroll
    for (int i = 0; i < 4; ++i) {
      int r = rb + i * 32;
      ushort4 u;
      if constexpr (A_IS_F32) {
        u.x = f2b(aF[i].x); u.y = f2b(aF[i].y);
        u.z = f2b(aF[i].z); u.w = f2b(aF[i].w);
      } else {
        u = aU[i];
      }
      *(ushort4*)&Asl[buf][r * 40 + seg * 4] = u;
      *(ushort4*)&Bsl[buf][r * 40 + seg * 4] = bR[i];
    }
  };

  load_tiles(0);
  write_lds(0);
  __syncthreads();

#pragma unroll
  for (int it = 0; it < 8; ++it) {
    const int cur = it & 1;
    if (it < 7) load_tiles((it + 1) * 32);

    short8 afr[4], bfr[4];
#pragma unroll
    for (int mt = 0; mt < 4; ++mt)
      afr[mt] = *(const short8*)&Asl[cur][(wm * 64 + mt * 16 + qr) * 40 + quad * 8];
#pragma unroll
    for (int nt = 0; nt < 4; ++nt)
      bfr[nt] = *(const short8*)&Bsl[cur][(wn * 64 + nt * 16 + qr) * 40 + quad * 8];
#pragma unroll
    for (int mt = 0; mt < 4; ++mt)
#pragma unroll
      for (int nt = 0; nt < 4; ++nt)
        acc[mt][nt] = __builtin_amdgcn_mfma_f32_16x16x32_bf16(afr[mt], bfr[nt], acc[mt][nt], 0, 0, 0);

    if (it < 7) {
      write_lds(1 - cur);
      __syncthreads();
    }
  }

#pragma unroll
  for (int mt = 0; mt < 4; ++mt) {
#pragma unroll
    for (int i = 0; i < 4; ++i) {
      int gr = row0 + wm * 64 + mt * 16 + quad * 4 + i;
      if (gr < M) {
        float sc = dscale[gr];
#pragma unroll
        for (int nt = 0; nt < 4; ++nt) {
          int gc = col0 + wn * 64 + nt * 16 + qr;
          u16 val = f2b(acc[mt][nt][i] * sc);
          if constexpr (PLANAR_C)
            C[(size_t)(gc >> 5) * CPS + (size_t)gr * 32 + (gc & 31)] = val;
          else
            C[(size_t)gr * N + gc] = val;
        }
      }
    }
  }
}

// plain GEMM kernel (layer 2): planar C out; block (0,0) seeds the 4 H3 plane
// zero rows (must happen after csr_sort consumed the stage overlay).
template <bool A_IS_F32, bool PLANAR_C>
__global__ __launch_bounds__(256) void gemm_mfma(const void* __restrict__ Ap,
                                                 const u16* __restrict__ Bt,
                                                 const float* __restrict__ dscale,
                                                 u16* __restrict__ C, int M, int N,
                                                 u16* __restrict__ zrow) {
  if (zrow != nullptr && blockIdx.x == 0 && blockIdx.y == 0 && threadIdx.x < 128) {
    int t = threadIdx.x;  // 4 planes x 32 ch
    zrow[(size_t)(t >> 5) * CPS + (size_t)NN * 32 + (t & 31)] = 0;
  }
  __shared__ u16 Asl[2][5120];
  __shared__ u16 Bsl[2][5120];
  gemm_body<A_IS_F32, PLANAR_C>(Ap, Bt, dscale, C, M, N, blockIdx.x, blockIdx.y, Asl, Bsl);
}

// fused: GEMM1 (blocks [0,ngb), planar Hb out) + pass-A bucket scatter
__global__ __launch_bounds__(256) void gemm1_scatter(const float* __restrict__ x,
                                                     const u16* __restrict__ W1t,
                                                     const float* __restrict__ dinv,
                                                     u16* __restrict__ Hb, int M, int N,
                                                     int ngb,
                                                     const int* __restrict__ row,
                                                     const int* __restrict__ col,
                                                     int* __restrict__ bcur,
                                                     uint2* __restrict__ stage, int E) {
  __shared__ u16 ABsl[4][5120];  // 40KB: GEMM A/B double-buffer OR pass-A staging
  int b = blockIdx.x;
  if (b < ngb) {
    gemm_body<true, true>(x, W1t, dinv, Hb, M, N, b & 1, b >> 1,
                          *reinterpret_cast<u16(*)[2][5120]>(&ABsl[0]),
                          *reinterpret_cast<u16(*)[2][5120]>(&ABsl[2]));
  } else {
    uint2* pairs = (uint2*)ABsl;                       // 4096 pairs = 32KB
    int* hcnt = (int*)((char*)ABsl + 32768);           // [256]
    int* hscan = hcnt + 256;                           // [256]
    int* hbase = hscan + 256;                          // [256]
    int* lcur = hbase + 256;                           // [256]

    const int tid = threadIdx.x;
    const int blk = b - ngb;
    const int e0 = blk * CHUNK;

    hcnt[tid] = 0;
    __syncthreads();

    int ecol[16], erow[16];
#pragma unroll
    for (int j = 0; j < 16; ++j) {
      int e = e0 + j * 256 + tid;
      if (e < E) {
        ecol[j] = col[e];
        erow[j] = row[e];
        atomicAdd(&hcnt[ecol[j] >> 8], 1);
      } else {
        ecol[j] = -1;
      }
    }
    __syncthreads();

    hscan[tid] = hcnt[tid];
    __syncthreads();
#pragma unroll
    for (int off = 1; off < 256; off <<= 1) {
      int t = (tid >= off) ? hscan[tid - off] : 0;
      __syncthreads();
      hscan[tid] += t;
      __syncthreads();
    }

    lcur[tid] = 0;
    if (hcnt[tid] > 0) hbase[tid] = atomicAdd(&bcur[tid], hcnt[tid]);
    __syncthreads();

#pragma unroll
    for (int j = 0; j < 16; ++j) {
      if (ecol[j] >= 0) {
        int bk = ecol[j] >> 8;
        int p = atomicAdd(&lcur[bk], 1);
        pairs[(hscan[bk] - hcnt[bk]) + p] = make_uint2((unsigned)erow[j], (unsigned)ecol[j]);
      }
    }
    __syncthreads();

    int mtot = hscan[255];
    for (int s = tid; s < mtot; s += 256) {
      uint2 pr = pairs[s];
      int bk = (int)(pr.y >> 8);
      stage[hbase[bk] + (s - (hscan[bk] - hcnt[bk]))] = pr;
    }
  }
}

// pass B: per-bucket counting-sort to exact (padded) csr positions, u16 output.
// Self-loop first per node; ALL pad slots pre-filled with NN (zero row).
// mreal recovered from bcur (post-scatter cursor) since bucket size is padded.
__global__ __launch_bounds__(256) void csr_sort(const uint2* __restrict__ stage,
                                                const int* __restrict__ row_off,
                                                const int* __restrict__ bcur,
                                                u16* __restrict__ csrp) {
  __shared__ int cur[256];
  __shared__ u16 outb[CAP_B];
  const int b = blockIdx.x;
  const int base_node = b << 8;
  const int nnodes = min(256, NN - base_node);
  const int tid = threadIdx.x;
  const int bstart = row_off[base_node];
  const int bend = row_off[min(base_node + 256, NN)];
  const int m = bend - bstart;          // padded bucket size
  const int mm = min(m, CAP_B);
  for (int i = tid; i < mm; i += 256) outb[i] = (u16)NN;     // pad fill (LDS)
  for (int i = CAP_B + tid; i < m; i += 256) csrp[bstart + i] = (u16)NN;  // overflow pad fill
  __syncthreads();
  if (tid < nnodes) {
    int c0 = row_off[base_node + tid] - bstart;
    outb[c0] = (u16)(base_node + tid);  // self-loop first
    cur[tid] = c0 + 1;
  }
  __syncthreads();
  const int mreal = bcur[b] - bstart - 0;  // staged real edges (bcur advanced past bstart)
  for (int i = tid; i < mreal; i += 256) {
    uint2 pr = stage[bstart + i];
    int cl = ((int)pr.y - base_node) & 255;  // defensive
    int p = atomicAdd(&cur[cl], 1);
    if (p < CAP_B) outb[p] = (u16)pr.x;
    else if (bstart + p < NETP) csrp[bstart + p] = (u16)pr.x;  // bounded fallback
  }
  __syncthreads();
  for (int i = tid; i < mm; i += 256) csrp[bstart + i] = outb[i];
}

// ---------------- aggregation: planar XCD slices, 4-way window-split waves ----------------
// out[v][cg] = dinv[v] * sum_{slots of v incl self & pads} H[slice][idx][c] + bias.
// r11 post-mortem: FETCH at compulsory (40MB) but VALUBusy only 40% — waves
// carried ~3Kcy of work across ~36Kcy lifetimes: stall = poor phase diversity
// + degree imbalance (wave trip = max over its 16 nodes). This round: 4x finer
// decomposition. Wave = 4 nodes x 4 WINDOW-GROUPS x 4 ch-quads; group wg
// handles windows wg, wg+4, ... of its node -> per-lane trips drop ~4x, wave
// count x4 (12 occupancy rounds), load balance flattens, coalescing unchanged
// (4 consecutive lanes still cover one 64B row). Epilogue: 2 extra shfl_xor
// (bits 2,3) fold window groups; wg==0 lanes write. Traffic identical to r11.
template <int NPL, int OUTC, bool RELU_BF16>
__global__ __launch_bounds__(256) void agg_gather(const u16* __restrict__ h,
                                                  const int* __restrict__ row_off,
                                                  const u16* __restrict__ csrp,
                                                  const float* __restrict__ dinv,
                                                  const float* __restrict__ bias,
                                                  void* __restrict__ outp) {
  const int slice = blockIdx.x % NPL;
  const int wave = threadIdx.x >> 6;
  const int lane = threadIdx.x & 63;
  const int nd = lane >> 4;            // node within wave (0..3)
  const int wg = (lane >> 2) & 3;      // window group (0..3)
  const int c = lane & 3;              // 8-ch segment (16B)
  const int v = (blockIdx.x / NPL) * 16 + wave * 4 + nd;
  if (v >= NN) return;                 // no barriers below: divergence safe
  const u16* hpl = h + (size_t)slice * CPS;
  const int beg = row_off[v], end = row_off[v + 1];  // 8-aligned
  const int nw = (end - beg) >> 3;     // windows (>=1)
  const int coff = c * 8;

  f32x2 a0 = {}, a1 = {}, a2 = {}, a3 = {};
  for (int w = wg; w < nw; w += 4) {
    ushort8 cw = *(const ushort8*)&csrp[beg + w * 8];  // aligned 16B
    u32x4 g0 = *(const u32x4*)&hpl[(size_t)cw[0] * 32 + coff];
    u32x4 g1 = *(const u32x4*)&hpl[(size_t)cw[1] * 32 + coff];
    u32x4 g2 = *(const u32x4*)&hpl[(size_t)cw[2] * 32 + coff];
    u32x4 g3 = *(const u32x4*)&hpl[(size_t)cw[3] * 32 + coff];
    u32x4 g4 = *(const u32x4*)&hpl[(size_t)cw[4] * 32 + coff];
    u32x4 g5 = *(const u32x4*)&hpl[(size_t)cw[5] * 32 + coff];
    u32x4 g6 = *(const u32x4*)&hpl[(size_t)cw[6] * 32 + coff];
    u32x4 g7 = *(const u32x4*)&hpl[(size_t)cw[7] * 32 + coff];
#pragma unroll
    for (int q = 0; q < 4; ++q) {
      f32x2 t;
      f32x2 acc = {};
      t[0] = __uint_as_float(g0[q] << 16); t[1] = __uint_as_float(g0[q] & 0xffff0000u); acc += t;
      t[0] = __uint_as_float(g1[q] << 16); t[1] = __uint_as_float(g1[q] & 0xffff0000u); acc += t;
      t[0] = __uint_as_float(g2[q] << 16); t[1] = __uint_as_float(g2[q] & 0xffff0000u); acc += t;
      t[0] = __uint_as_float(g3[q] << 16); t[1] = __uint_as_float(g3[q] & 0xffff0000u); acc += t;
      t[0] = __uint_as_float(g4[q] << 16); t[1] = __uint_as_float(g4[q] & 0xffff0000u); acc += t;
      t[0] = __uint_as_float(g5[q] << 16); t[1] = __uint_as_float(g5[q] & 0xffff0000u); acc += t;
      t[0] = __uint_as_float(g6[q] << 16); t[1] = __uint_as_float(g6[q] & 0xffff0000u); acc += t;
      t[0] = __uint_as_float(g7[q] << 16); t[1] = __uint_as_float(g7[q] & 0xffff0000u); acc += t;
      if (q == 0) a0 += acc;
      else if (q == 1) a1 += acc;
      else if (q == 2) a2 += acc;
      else a3 += acc;
    }
  }
  float aa[8] = {a0[0], a0[1], a1[0], a1[1], a2[0], a2[1], a3[0], a3[1]};
  // fold the 4 window groups (lane bits 2,3) — stays within the 16-lane node group
#pragma unroll
  for (int i = 0; i < 8; ++i) {
    aa[i] += __shfl_xor(aa[i], 4, 64);
    aa[i] += __shfl_xor(aa[i], 8, 64);
  }
  if (wg == 0) {
    const int cg = slice * 32 + coff;
    float dv = dinv[v];
    float4 bv0 = *(const float4*)&bias[cg];
    float4 bv1 = *(const float4*)&bias[cg + 4];
    float bb[8] = {bv0.x, bv0.y, bv0.z, bv0.w, bv1.x, bv1.y, bv1.z, bv1.w};
    if constexpr (RELU_BF16) {
      u16* o = (u16*)outp;
      ushort8 ov;
#pragma unroll
      for (int i = 0; i < 8; ++i) ov[i] = (short)f2b(fmaxf(aa[i] * dv + bb[i], 0.f));
      *(ushort8*)&o[(size_t)v * OUTC + cg] = ov;
    } else {
      float* o = (float*)outp;
      float ov[8];
#pragma unroll
      for (int i = 0; i < 8; ++i) ov[i] = aa[i] * dv + bb[i];
      *(float4*)&o[(size_t)v * OUTC + cg] = make_float4(ov[0], ov[1], ov[2], ov[3]);
      *(float4*)&o[(size_t)v * OUTC + cg + 4] = make_float4(ov[4], ov[5], ov[6], ov[7]);
    }
  }
}

// ---------------- launch ----------------

extern "C" void kernel_launch(void* const* d_in, const int* in_sizes, int n_in,
                              void* d_out, int out_size, void* d_ws, size_t ws_size,
                              hipStream_t stream) {
  const float* x = (const float*)d_in[0];
  const int* ei = (const int*)d_in[1];
  const float* W1 = (const float*)d_in[2];
  const float* b1 = (const float*)d_in[3];
  const float* W2 = (const float*)d_in[4];
  const float* b2 = (const float*)d_in[5];
  float* out = (float*)d_out;

  const int* row = ei;
  const int* col = ei + NE;

  const int NB = (NN + 255) / 256;  // 196

  // workspace layout — Hb: 8 planar planes [(NN+1)x32]; H3b: 4 planar planes.
  u16* Hb = (u16*)d_ws;                       // 8*CPS bf16, pre-scaled by dinv[row]
  u16* H2b = Hb + (size_t)(NN + 1) * 256;     // [NN,256] bf16 (standard layout)
  u16* H3b = H2b + (size_t)NN * 256;          // 4*CPS bf16, pre-scaled
  u16* W1t = H3b + (size_t)(NN + 1) * 128;    // [256,256] bf16
  u16* W2t = W1t + 256 * 256;                 // [128,256] bf16
  int* cnt = (int*)(W2t + 128 * 256);         // [NN]
  int* row_off = cnt + NN;                    // [NN+4] (padded)
  int* bcur = row_off + NN + 4;               // [256] per-bucket stage cursors
  float* dinv = (float*)(bcur + 256);         // [NN]
  int* bsum = (int*)(dinv + NN);              // [200]
  int* boff = bsum + 200;                     // [200]
  u16* csrp = (u16*)(boff + 200);             // [NETP+64] padded u16 indices
  // stage overlays H3b (padded coords, max 1.2M pairs = 9.6MB <= 12.8MB);
  // H3 zero rows re-seeded in gemm2 (after csr_sort consumed the overlay).
  uint2* stage = (uint2*)H3b;                 // [<=NETP] (row,col) pairs

  convw_zero<<<256 + NB + 1, 256, 0, stream>>>(W1, W2, W1t, W2t, cnt, Hb, NB);
  hist_kernel<<<(NE + 255) / 256, 256, 0, stream>>>(col, cnt, NE);
  scan1_kernel<<<NB, 256, 0, stream>>>(cnt, bsum, NN);
  scan2_kernel<<<1, 256, 0, stream>>>(bsum, boff, row_off, NB, NN);
  scan3_kernel<<<NB, 256, 0, stream>>>(cnt, boff, row_off, bcur, dinv, NN);

  // fused: GEMM1 (planar Hb = dinv * (x@W1), bf16) concurrent with pass-A scatter
  {
    const int ngb = (HID_C / 128) * ((NN + 127) / 128);  // 782
    gemm1_scatter<<<ngb + NPA, 256, 0, stream>>>(x, W1t, dinv, Hb, NN, HID_C, ngb,
                                                 row, col, bcur, stage, NE);
  }
  csr_sort<<<NBUCK, 256, 0, stream>>>(stage, row_off, bcur, csrp);

  const int NGB = (NN + 15) / 16;  // 3125 blocks of 16 nodes
  // agg1: 8 planes x 32 ch, plane==XCD via blockIdx%8; out = H2b [NN,256] bf16+relu
  agg_gather<8, 256, true><<<NGB * 8, 256, 0, stream>>>(
      Hb, row_off, csrp, dinv, b1, H2b);

  {
    dim3 grid(OUT_C / 128, (NN + 127) / 128);
    gemm_mfma<false, true><<<grid, 256, 0, stream>>>(H2b, W2t, dinv, H3b, NN, OUT_C, H3b);
  }

  // agg2: 4 planes x 32 ch; out = final f32 [NN,128]
  agg_gather<4, 128, false><<<NGB * 4, 256, 0, stream>>>(
      H3b, row_off, csrp, dinv, b2, out);
}